// Round 3
// baseline (269.288 us; speedup 1.0000x reference)
//
#include <hip/hip_runtime.h>

// MultiHashtable4d: 16-level 4D hash-grid interpolation.
// One thread per (point-pair, level l); l is wave-uniform so per-level params
// are scalar and the direct/hash branch is uniform.
//
// R2: XCD-pinned level-major mapping (blockIdx%8 == level%8) keeps one 4.19MB
//     table per XCD-L2 -> FETCH 902->242MB, 321->193us.
// R3: explicit phase structure: neutral.
// R4: table owns L2 (streaming nt): FETCH ~compulsory.
// R5: sc0 L1-bypass on gathers: -2.7%.
// R6: 8/8 split cached vs sc0: null -> L1-miss and bypass paths share one
//     tracking/service resource.
// R7: DECISIVE TEST (and the win if it works): server-limited vs
//     in-flight-limited. Throughput is pinned at 9.5 req/cy/XCD across R3-R6;
//     implied latency ~1100cy (5x unloaded) says queue-saturated server.
//     2 points/thread software pipeline: issue 32 gathers, consume A at
//     vmcnt(16), consume B at vmcnt(1) (A-store holds 1 slot). 16 waves/CU
//     (128-VGPR cap) x 32 outstanding = 512 in-flight vs 384 today.
//     If in-flight-limited -> ~140-150us. If null -> server floor confirmed
//     by 5 independent perturbations -> ROOFLINE.

#define FDIM 2

using f32x2 = __attribute__((ext_vector_type(2))) float;

__global__ __launch_bounds__(256, 4) void mh4d_kernel(
    const float* __restrict__ xyz,     // [N,3]
    const float* __restrict__ tt,      // [N,1]
    const float* __restrict__ data,    // [L,T,FDIM]
    const float* __restrict__ bounds,  // [2,4]
    const float* __restrict__ es,      // [L,4] entrys_size
    const int*   __restrict__ en,      // [L,4] entrys_num
    const int*   __restrict__ p_sh,    // start_hash
    const int*   __restrict__ p_sf,    // start_frame
    const int*   __restrict__ p_tf,    // total_frame
    float* __restrict__ out,           // [N, L*FDIM]
    int N, int L, unsigned int T, unsigned long long M,
    unsigned int bpl)                  // blocks per level (512 points/block)
{
    int l, chunk;
    if ((L & 7) == 0) {
        // XCD-pinned decode: xb = b%8 selects the XCD *and* the level group.
        const unsigned int xb  = blockIdx.x & 7u;
        const unsigned int rem = blockIdx.x >> 3;
        const unsigned int p   = rem / bpl;      // phase: which level on this XCD
        chunk = (int)(rem - p * bpl);
        l     = (int)(p * 8u + xb);
    } else {
        l     = (int)(blockIdx.x / bpl);
        chunk = (int)(blockIdx.x - (unsigned)l * bpl);
    }
    // two points per thread: A = first half of the block's 512-point span
    const int nA = chunk * 2 * (int)blockDim.x + (int)threadIdx.x;
    if (nA >= N) return;
    const int nBr = nA + (int)blockDim.x;
    const bool hasB = nBr < N;
    const int nB = hasB ? nBr : nA;   // safe duplicate on tail; store suppressed

    const int start_hash = *p_sh;
    // reference: t - start_frame/(total_frame-1), scalar rounded to f32
    const float tshift = (float)((double)(*p_sf) / (double)(*p_tf - 1));

    // wave-uniform per-level params -> scalar loads
    const float es0 = es[l * 4 + 0], es1 = es[l * 4 + 1];
    const float es2 = es[l * 4 + 2], es3 = es[l * 4 + 3];
    const int e0 = en[l * 4 + 0], e1 = en[l * 4 + 1];
    const int e2 = en[l * 4 + 2], e3 = en[l * 4 + 3];

    const float b0 = bounds[0], b1 = bounds[1], b2 = bounds[2], b3 = bounds[3];

    // streaming inputs: nontemporal — do not let them evict table lines in L2
#define LOADP(S, n) \
    const float x##S  = __builtin_nontemporal_load(&xyz[(n) * 3 + 0]); \
    const float y##S  = __builtin_nontemporal_load(&xyz[(n) * 3 + 1]); \
    const float z##S  = __builtin_nontemporal_load(&xyz[(n) * 3 + 2]); \
    const float tv##S = __builtin_nontemporal_load(&tt[(n)]) - tshift;

    LOADP(A, nA)
    LOADP(B, nB)

    // Corner ints: trunc(f + offset) computed IN f32 — must NOT fold to
    // trunc(f)+1 (f32 rounding near integers changes the index like the ref).
    // offsets from UNCLIPPED corner-0 trunc (ref computes offset before clip).
#define CORNERS(S) \
    const float f0##S = (x##S  - b0) / es0; \
    const float f1##S = (y##S  - b1) / es1; \
    const float f2##S = (z##S  - b2) / es2; \
    const float f3##S = (tv##S - b3) / es3; \
    int lo0##S = (int)f0##S, hi0##S = (int)(f0##S + 1.0f); \
    int lo1##S = (int)f1##S, hi1##S = (int)(f1##S + 1.0f); \
    int lo2##S = (int)f2##S, hi2##S = (int)(f2##S + 1.0f); \
    int lo3##S = (int)f3##S, hi3##S = (int)(f3##S + 1.0f); \
    const float o0##S = f0##S - (float)lo0##S; \
    const float o1##S = f1##S - (float)lo1##S; \
    const float o2##S = f2##S - (float)lo2##S; \
    const float o3##S = f3##S - (float)lo3##S; \
    lo0##S = min(max(lo0##S, 0), e0 - 1);  hi0##S = min(max(hi0##S, 0), e0 - 1); \
    lo1##S = min(max(lo1##S, 0), e1 - 1);  hi1##S = min(max(hi1##S, 0), e1 - 1); \
    lo2##S = min(max(lo2##S, 0), e2 - 1);  hi2##S = min(max(hi2##S, 0), e2 - 1); \
    lo3##S = min(max(lo3##S, 0), e3 - 1);  hi3##S = min(max(hi3##S, 0), e3 - 1);

    CORNERS(A)
    CORNERS(B)

    // hash path: xor of 64-bit prime products, mod T via magic multiply
    // direct path: ((x*e1+y)*e2+z)*e3+t, always < T so 32-bit is exact
#define INDICES(S, r) \
    if (l >= start_hash) { \
        const unsigned long long hx[2] = { (unsigned long long)(unsigned)lo0##S, \
                                           (unsigned long long)(unsigned)hi0##S }; \
        const unsigned long long hy[2] = { (unsigned long long)(unsigned)lo1##S * 19349663ull, \
                                           (unsigned long long)(unsigned)hi1##S * 19349663ull }; \
        const unsigned long long hz[2] = { (unsigned long long)(unsigned)lo2##S * 83492791ull, \
                                           (unsigned long long)(unsigned)hi2##S * 83492791ull }; \
        const unsigned long long ht[2] = { (unsigned long long)(unsigned)lo3##S * 73856093ull, \
                                           (unsigned long long)(unsigned)hi3##S * 73856093ull }; \
        _Pragma("unroll") \
        for (int c = 0; c < 16; ++c) { \
            const unsigned long long v = \
                hx[(c >> 3) & 1] ^ hy[(c >> 2) & 1] ^ hz[(c >> 1) & 1] ^ ht[c & 1]; \
            const unsigned long long q = __umul64hi(v, M);   /* q in {Q-1, Q} */ \
            unsigned int rr = (unsigned int)v - (unsigned int)q * T; \
            if (rr >= T) rr -= T; \
            (r)[c] = rr; \
        } \
    } else { \
        _Pragma("unroll") \
        for (int c = 0; c < 16; ++c) { \
            const unsigned int ix = (unsigned)((c & 8) ? hi0##S : lo0##S); \
            const unsigned int iy = (unsigned)((c & 4) ? hi1##S : lo1##S); \
            const unsigned int iz = (unsigned)((c & 2) ? hi2##S : lo2##S); \
            const unsigned int it = (unsigned)((c & 1) ? hi3##S : lo3##S); \
            unsigned int ind = ix * (unsigned)e1 + iy; \
            ind = ind * (unsigned)e2 + iz; \
            ind = ind * (unsigned)e3 + it; \
            (r)[c] = ind; \
        } \
    }

    const float* __restrict__ base = data + (size_t)l * (size_t)T * FDIM;

    // PIN: every compiler-visible load above is consumed above. The compiler's
    // waitcnt pass cannot count our asm VMEM ops; if any of its counted waits
    // landed after our gathers it would over-drain (serialize). No compiler
    // load consumption may be scheduled past this point.
    __builtin_amdgcn_sched_barrier(0);

    // ---- issue 16 A-gathers, then 16 B-gathers (sc0 = SE scope, L1 bypass) ----
    unsigned int rA[16];
    INDICES(A, rA)
    f32x2 valsA[16];
    #pragma unroll
    for (int c = 0; c < 16; ++c)
        asm volatile("global_load_dwordx2 %0, %1, %2 sc0"
                     : "=v"(valsA[c]) : "v"(rA[c] * 8u), "s"(base));

    unsigned int rB[16];
    INDICES(B, rB)
    f32x2 valsB[16];
    #pragma unroll
    for (int c = 0; c < 16; ++c)
        asm volatile("global_load_dwordx2 %0, %1, %2 sc0"
                     : "=v"(valsB[c]) : "v"(rB[c] * 8u), "s"(base));

    // weights: clip(1-o,0,1)/clip(o,0,1); hierarchical products ((wx*wy)*wz)*wt
#define WEIGHTS(S, w) \
    { \
        const float wx[2] = { fminf(fmaxf(1.0f - o0##S, 0.0f), 1.0f), fminf(fmaxf(o0##S, 0.0f), 1.0f) }; \
        const float wy[2] = { fminf(fmaxf(1.0f - o1##S, 0.0f), 1.0f), fminf(fmaxf(o1##S, 0.0f), 1.0f) }; \
        const float wz[2] = { fminf(fmaxf(1.0f - o2##S, 0.0f), 1.0f), fminf(fmaxf(o2##S, 0.0f), 1.0f) }; \
        const float wt[2] = { fminf(fmaxf(1.0f - o3##S, 0.0f), 1.0f), fminf(fmaxf(o3##S, 0.0f), 1.0f) }; \
        float pxy[4], pxyz[8]; \
        _Pragma("unroll") for (int a = 0; a < 2; ++a) \
            _Pragma("unroll") for (int b = 0; b < 2; ++b) pxy[a * 2 + b] = wx[a] * wy[b]; \
        _Pragma("unroll") for (int a = 0; a < 4; ++a) \
            _Pragma("unroll") for (int b = 0; b < 2; ++b) pxyz[a * 2 + b] = pxy[a] * wz[b]; \
        _Pragma("unroll") for (int a = 0; a < 8; ++a) \
            _Pragma("unroll") for (int b = 0; b < 2; ++b) (w)[a * 2 + b] = pxyz[a] * wt[b]; \
    }

    float wA[16];
    WEIGHTS(A, wA)

    // ---- consume A: wait until only B's 16 gathers remain in flight ----
    asm volatile("s_waitcnt vmcnt(16)" ::: "memory");
    __builtin_amdgcn_sched_barrier(0);

    float accxA = 0.0f, accyA = 0.0f;
    #pragma unroll
    for (int c = 0; c < 16; ++c) {
        accxA = fmaf(wA[c], valsA[c][0], accxA);
        accyA = fmaf(wA[c], valsA[c][1], accyA);
    }
    {
        unsigned long long packed =
            ((unsigned long long)__float_as_uint(accyA) << 32) | (unsigned long long)__float_as_uint(accxA);
        unsigned long long* op =
            (unsigned long long*)(out + ((size_t)nA * (size_t)L + (size_t)l) * FDIM);
        __builtin_nontemporal_store(packed, op);   // occupies 1 vmcnt slot
    }

    float wB[16];
    WEIGHTS(B, wB)

    // ---- consume B: vmcnt(1) allows the A-store (youngest op) to stay in flight;
    // in-order retirement guarantees the 16 older B-gathers are done ----
    asm volatile("s_waitcnt vmcnt(1)" ::: "memory");
    __builtin_amdgcn_sched_barrier(0);

    float accxB = 0.0f, accyB = 0.0f;
    #pragma unroll
    for (int c = 0; c < 16; ++c) {
        accxB = fmaf(wB[c], valsB[c][0], accxB);
        accyB = fmaf(wB[c], valsB[c][1], accyB);
    }
    if (hasB) {
        unsigned long long packed =
            ((unsigned long long)__float_as_uint(accyB) << 32) | (unsigned long long)__float_as_uint(accxB);
        unsigned long long* op =
            (unsigned long long*)(out + ((size_t)nB * (size_t)L + (size_t)l) * FDIM);
        __builtin_nontemporal_store(packed, op);
    }
}

extern "C" void kernel_launch(void* const* d_in, const int* in_sizes, int n_in,
                              void* d_out, int out_size, void* d_ws, size_t ws_size,
                              hipStream_t stream) {
    const float* xyz    = (const float*)d_in[0];
    const float* tt     = (const float*)d_in[1];
    const float* data   = (const float*)d_in[2];
    const float* bounds = (const float*)d_in[3];
    // d_in[4] = offsets: the 16 binary corners are hard-coded (matches reference OFFSETS)
    const float* es     = (const float*)d_in[5];
    const int*   en     = (const int*)d_in[6];
    const int*   p_sh   = (const int*)d_in[7];
    const int*   p_sf   = (const int*)d_in[8];
    const int*   p_tf   = (const int*)d_in[9];
    float*       out    = (float*)d_out;

    const int N = in_sizes[0] / 3;
    const int L = in_sizes[5] / 4;                       // entrys_size is [L,4]
    const unsigned int T = (unsigned int)(in_sizes[2] / (L * FDIM)); // data is [L,T,F]
    const unsigned long long M = ~0ull / (unsigned long long)T;      // floor(2^64/T), T prime

    const int threads = 256;
    const int ppb = 2 * threads;                          // 2 points per thread
    const unsigned int bpl = (unsigned)((N + ppb - 1) / ppb); // blocks per level
    dim3 grid(bpl * (unsigned)L);
    mh4d_kernel<<<grid, threads, 0, stream>>>(xyz, tt, data, bounds, es, en,
                                              p_sh, p_sf, p_tf, out,
                                              N, L, T, M, bpl);
}